// Round 3
// baseline (486.827 us; speedup 1.0000x reference)
//
#include <hip/hip_runtime.h>
#include <cstdint>

typedef __attribute__((ext_vector_type(8))) short short8;
typedef __attribute__((ext_vector_type(4))) float f32x4;
typedef unsigned short u16;

__device__ __forceinline__ float b2f(u16 u) {
  union { unsigned int i; float f; } v; v.i = ((unsigned int)u) << 16; return v.f;
}
__device__ __forceinline__ u16 f2b(float f) {
  union { float f; unsigned int i; } v; v.f = f;
  unsigned int x = v.i;
  return (u16)((x + 0x7fffu + ((x >> 16) & 1u)) >> 16);
}
__device__ __forceinline__ float silu_f(float x) { return x / (1.0f + __expf(-x)); }

// dtype-flexible load: flag==1 -> float32 data, flag==0 -> bf16 data.
__device__ __forceinline__ float loadF(const void* p, long i, int isf32) {
  if (isf32) return ((const float*)p)[i];
  return b2f(((const u16*)p)[i]);
}

struct Ptrs { const void* p[20]; int n[20]; };

// f32 prepped-weight layout (float offsets)
#define FW_NW1 0
#define FW_NW2 4096
#define FW_UW1 8192
#define FW_UW2 12288
#define FW_EW1 16384
#define FW_NB1 16768
#define FW_NB2 16832
#define FW_UB1 16896
#define FW_UB2 16960
#define FW_EB1 17024
#define FW_EB2 17088
#define FW_MB1 17152
#define FW_MB2 17216
#define FW_TOTAL 17280

// bf16 transposed image layout (u16 offsets):
// [0,4608)      ew2T [64 n][72 k] (k<64 real)
// [4608,13312)  mw1T [64 n][136 k] (k<128 real)
// [13312,17920) mw2T [64 n][72 k]
#define IMG_EW2 0
#define IMG_MW1 4608
#define IMG_MW2 13312
#define IMG_TOTAL 17920

// ---------------------------------------------------------------------------
// Kernel 0: per-tensor dtype detection.
// f32 data viewed as u16: even indices are low mantissa halves -> ~12% have
// bf16-exponent-field >= 0xC0 (|x|>=2^65). Genuine bf16 N(0,1)/uniform: zero.
// ---------------------------------------------------------------------------
__global__ __launch_bounds__(256) void detect_k(Ptrs a, int* flags) {
  int j = blockIdx.x;
  const u16* q = (const u16*)a.p[j];
  int n = a.n[j];
  int m = n < 4096 ? n : 4096;   // first n u16s are in-bounds for either dtype
  int cnt = 0;
  for (int i = threadIdx.x; i < m; i += 256) {
    unsigned e = (q[i] >> 7) & 0xffu;
    if (e >= 0xC0u) cnt++;
  }
  __shared__ int tot;
  if (threadIdx.x == 0) tot = 0;
  __syncthreads();
  if (cnt) atomicAdd(&tot, cnt);
  __syncthreads();
  if (threadIdx.x == 0) flags[j] = (tot >= 2) ? 1 : 0;
}

// ---------------------------------------------------------------------------
// Kernel 1: weight prep. Edge/msg weights -> transposed bf16 MFMA image;
// node/upd weights + ew1 + all biases -> f32.
// Ptrs index map: 0 nf,1 npos,2 gpos,3 orient,4 nw1,5 nb1,6 nw2,7 nb2,
//                 8 ew1,9 eb1,10 ew2,11 eb2,12 mw1,13 mb1,14 mw2,15 mb2,
//                 16 uw1,17 ub1,18 uw2,19 ub2
// ---------------------------------------------------------------------------
__global__ __launch_bounds__(256) void prep_k(Ptrs a, const int* flags,
                                              u16* img, float* fw) {
  int i = blockIdx.x * 256 + threadIdx.x;
  if (i < IMG_TOTAL) {
    u16 val = 0;
    if (i < IMG_MW1) {
      int nn = i / 72, k = i % 72;
      if (k < 64) val = f2b(loadF(a.p[10], (long)k * 64 + nn, flags[10]));
    } else if (i < IMG_MW2) {
      int t2 = i - IMG_MW1; int nn = t2 / 136, k = t2 % 136;
      if (k < 128) val = f2b(loadF(a.p[12], (long)k * 64 + nn, flags[12]));
    } else {
      int t2 = i - IMG_MW2; int nn = t2 / 72, k = t2 % 72;
      if (k < 64) val = f2b(loadF(a.p[14], (long)k * 64 + nn, flags[14]));
    }
    img[i] = val;
  } else if (i < IMG_TOTAL + FW_TOTAL) {
    int j = i - IMG_TOTAL;
    float v;
    if (j < 4096)            v = loadF(a.p[4],  j,          flags[4]);
    else if (j < 8192)       v = loadF(a.p[6],  j - 4096,   flags[6]);
    else if (j < 12288)      v = loadF(a.p[16], j - 8192,   flags[16]);
    else if (j < 16384)      v = loadF(a.p[18], j - 12288,  flags[18]);
    else if (j < 16768)      v = loadF(a.p[8],  j - 16384,  flags[8]);
    else {
      int b = j - 16768; int seg = b >> 6, c = b & 63;
      const void* bp; int bf;
      switch (seg) {
        case 0: bp = a.p[5];  bf = flags[5];  break;
        case 1: bp = a.p[7];  bf = flags[7];  break;
        case 2: bp = a.p[17]; bf = flags[17]; break;
        case 3: bp = a.p[19]; bf = flags[19]; break;
        case 4: bp = a.p[9];  bf = flags[9];  break;
        case 5: bp = a.p[11]; bf = flags[11]; break;
        case 6: bp = a.p[13]; bf = flags[13]; break;
        default: bp = a.p[15]; bf = flags[15]; break;
      }
      v = loadF(bp, c, bf);
    }
    fw[j] = v;
  }
}

// ---------------------------------------------------------------------------
// Kernel 2: node MLP, f32 VALU. 64 rows/block, 4x4 reg tile per thread.
// Output h_node bf16 (MFMA A-operand for the message layer).
// ---------------------------------------------------------------------------
__global__ __launch_bounds__(256) void node_mlp(
    const void* x, const int* flags, const float* fw, u16* out, int nrows)
{
  __shared__ float xs[64][68];
  __shared__ float w1s[64][68];
  __shared__ float w2s[64][68];
  __shared__ float b1s[64];
  __shared__ float b2s[64];
  const int t = threadIdx.x;
  const int xf = flags[0];
  const long rbase = (long)blockIdx.x * 64;
  for (int i = t; i < 4096; i += 256) {
    int k = i >> 6, cc = i & 63;
    w1s[k][cc] = fw[FW_NW1 + i];
    w2s[k][cc] = fw[FW_NW2 + i];
  }
  if (t < 64) { b1s[t] = fw[FW_NB1 + t]; b2s[t] = fw[FW_NB2 + t]; }
  {
    int row = t >> 2, ch = t & 3;
    long rg = rbase + row;
    if (rg < nrows) {
      if (xf) {
        const float* xp = (const float*)x + rg * 64 + ch * 16;
#pragma unroll
        for (int m = 0; m < 16; ++m) xs[row][ch * 16 + m] = xp[m];
      } else {
        const u16* xp = (const u16*)x + rg * 64 + ch * 16;
#pragma unroll
        for (int m = 0; m < 16; ++m) xs[row][ch * 16 + m] = b2f(xp[m]);
      }
    } else {
#pragma unroll
      for (int m = 0; m < 16; ++m) xs[row][ch * 16 + m] = 0.f;
    }
  }
  __syncthreads();
  const int r0 = (t >> 4) * 4, c0 = (t & 15) * 4;
  float acc[4][4];
#pragma unroll
  for (int i = 0; i < 4; ++i)
#pragma unroll
    for (int j = 0; j < 4; ++j) acc[i][j] = b1s[c0 + j];
  for (int k = 0; k < 64; ++k) {
    float w0 = w1s[k][c0], w1v = w1s[k][c0 + 1], w2v = w1s[k][c0 + 2], w3v = w1s[k][c0 + 3];
#pragma unroll
    for (int i = 0; i < 4; ++i) {
      float a = xs[r0 + i][k];
      acc[i][0] = fmaf(a, w0, acc[i][0]);
      acc[i][1] = fmaf(a, w1v, acc[i][1]);
      acc[i][2] = fmaf(a, w2v, acc[i][2]);
      acc[i][3] = fmaf(a, w3v, acc[i][3]);
    }
  }
  __syncthreads();
#pragma unroll
  for (int i = 0; i < 4; ++i)
#pragma unroll
    for (int j = 0; j < 4; ++j) xs[r0 + i][c0 + j] = silu_f(acc[i][j]);
  __syncthreads();
  float acc2[4][4];
#pragma unroll
  for (int i = 0; i < 4; ++i)
#pragma unroll
    for (int j = 0; j < 4; ++j) acc2[i][j] = b2s[c0 + j];
  for (int k = 0; k < 64; ++k) {
    float w0 = w2s[k][c0], w1v = w2s[k][c0 + 1], w2v = w2s[k][c0 + 2], w3v = w2s[k][c0 + 3];
#pragma unroll
    for (int i = 0; i < 4; ++i) {
      float a = xs[r0 + i][k];
      acc2[i][0] = fmaf(a, w0, acc2[i][0]);
      acc2[i][1] = fmaf(a, w1v, acc2[i][1]);
      acc2[i][2] = fmaf(a, w2v, acc2[i][2]);
      acc2[i][3] = fmaf(a, w3v, acc2[i][3]);
    }
  }
#pragma unroll
  for (int i = 0; i < 4; ++i) {
    long rg = rbase + r0 + i;
    if (rg < nrows) {
#pragma unroll
      for (int j = 0; j < 4; ++j) out[rg * 64 + c0 + j] = f2b(acc2[i][j]);
    }
  }
}

// ---------------------------------------------------------------------------
// Kernel 3: edge pipeline. 256 thr/block, ETILES x 64 edges per block.
// S1 (edge MLP L1, K=6) in f32 VALU; S2/S3/S4 via mfma_f32_16x16x32_bf16.
// A-frag: lane holds A[m=lane&15][k=(lane>>4)*8+j].
// B-frag: lane holds B[k=(lane>>4)*8+j][n=lane&15] (from transposed [n][k] image).
// C/D: reg r -> (row=(lane>>4)*4+r, col=lane&15).
// ---------------------------------------------------------------------------
#define ETILES 4

__global__ __launch_bounds__(256, 2) void edge_kernel(
    const void* node_pos, const void* grid_pos, const void* orient,
    const int* __restrict__ eidx, const u16* __restrict__ h_node,
    const u16* __restrict__ img, const float* __restrict__ fw,
    const int* __restrict__ flags,
    float* __restrict__ sums, float* __restrict__ counts,
    long E, int G)
{
  __shared__ __align__(16) u16 wTs[IMG_TOTAL];
  __shared__ __align__(16) float eaf[64][8];   // edge_attr f32 (cols 0..5)
  __shared__ __align__(16) u16 hA[64][136];    // msg_in: 0-63 h_node, 64-127 e_feat2
  __shared__ __align__(16) u16 ef1[64][72];    // hidden activations (bf16)
  __shared__ float w1e[6][64];                 // ew1 f32
  __shared__ float biasE[4][64];               // eb1, eb2, mb1, mb2
  __shared__ int src_s[64];
  __shared__ int tgt_s[64];

  const int t = threadIdx.x;
  const int pf = flags[1], gf = flags[2], of = flags[3];

  {
    const short8* src = (const short8*)img;
    short8* dst = (short8*)wTs;
#pragma unroll
    for (int it = 0; it < 9; ++it) {
      int idx = t + 256 * it;
      if (idx < IMG_TOTAL / 8) dst[idx] = src[idx];
    }
  }
  for (int i = t; i < 384; i += 256) w1e[i / 64][i % 64] = fw[FW_EW1 + i];
  { int seg = t >> 6, cc = t & 63; biasE[seg][cc] = fw[FW_EB1 + seg * 64 + cc]; }

  const int lane = t & 63, w = t >> 6;
  const int q = lane >> 4, c = lane & 15;
  const int m0 = w * 16;
  const u16* wE2 = &wTs[IMG_EW2];
  const u16* wM1 = &wTs[IMG_MW1];
  const u16* wM2 = &wTs[IMG_MW2];
  const f32x4 z = {0.f, 0.f, 0.f, 0.f};

  for (int tile = 0; tile < ETILES; ++tile) {
    long base = ((long)blockIdx.x * ETILES + tile) * 64;
    if (base >= E) break;
    __syncthreads();  // protect LDS reuse from previous tile
    if (t < 64) {
      long eg = base + t;
      int s, tg;
      if (eg < E) { s = eidx[eg]; tg = eidx[E + eg]; }
      else { s = 0; tg = -1; }
      src_s[t] = s;
      tgt_s[t] = tg;
      bool valid = (tg >= 0) && (tg < G);
      if (valid) unsafeAtomicAdd(counts + tg, 1.0f);
      int tgc = valid ? tg : 0;
      float ps[3], rel[3], tr[3];
#pragma unroll
      for (int i = 0; i < 3; ++i) {
        ps[i] = loadF(node_pos, (long)s * 3 + i, pf);
        rel[i] = loadF(grid_pos, (long)tgc * 3 + i, gf) - ps[i];
      }
#pragma unroll
      for (int j = 0; j < 3; ++j) tr[j] = 0.f;
#pragma unroll
      for (int i = 0; i < 3; ++i)
#pragma unroll
        for (int j = 0; j < 3; ++j)
          tr[j] = fmaf(rel[i], loadF(orient, (long)s * 9 + i * 3 + j, of), tr[j]);
      eaf[t][0] = ps[0]; eaf[t][1] = ps[1]; eaf[t][2] = ps[2];
      eaf[t][3] = tr[0]; eaf[t][4] = tr[1]; eaf[t][5] = tr[2];
    }
    __syncthreads();  // src_s ready
    {
      int e = t >> 2, ch = t & 3;
      const u16* hp = h_node + (long)src_s[e] * 64 + ch * 16;
      short8 v0 = *(const short8*)hp;
      short8 v1 = *(const short8*)(hp + 8);
      *(short8*)&hA[e][ch * 16] = v0;
      *(short8*)&hA[e][ch * 16 + 8] = v1;
    }
    __syncthreads();  // eaf + hA(h_node half) ready

    // S1: edge MLP layer1 (K=6) in f32 VALU -> silu -> ef1 (bf16)
    {
      int e = t >> 2, c0 = (t & 3) * 16;
      float a0 = eaf[e][0], a1 = eaf[e][1], a2 = eaf[e][2];
      float a3 = eaf[e][3], a4 = eaf[e][4], a5 = eaf[e][5];
      __align__(16) u16 tmp[16];
#pragma unroll
      for (int j = 0; j < 16; ++j) {
        int cc = c0 + j;
        float acc = biasE[0][cc];
        acc = fmaf(a0, w1e[0][cc], acc);
        acc = fmaf(a1, w1e[1][cc], acc);
        acc = fmaf(a2, w1e[2][cc], acc);
        acc = fmaf(a3, w1e[3][cc], acc);
        acc = fmaf(a4, w1e[4][cc], acc);
        acc = fmaf(a5, w1e[5][cc], acc);
        tmp[j] = f2b(silu_f(acc));
      }
      *(short8*)&ef1[e][c0] = *(const short8*)tmp;
      *(short8*)&ef1[e][c0 + 8] = *(const short8*)(tmp + 8);
    }
    __syncthreads();
    // S2: edge MLP layer2 (K=64) -> hA cols 64..127 (bf16)
    {
      short8 a0 = *(const short8*)&ef1[m0 + c][q * 8];
      short8 a1 = *(const short8*)&ef1[m0 + c][32 + q * 8];
#pragma unroll
      for (int nt = 0; nt < 4; ++nt) {
        short8 b0 = *(const short8*)&wE2[(nt * 16 + c) * 72 + q * 8];
        short8 b1v = *(const short8*)&wE2[(nt * 16 + c) * 72 + 32 + q * 8];
        f32x4 acc = __builtin_amdgcn_mfma_f32_16x16x32_bf16(a0, b0, z, 0, 0, 0);
        acc = __builtin_amdgcn_mfma_f32_16x16x32_bf16(a1, b1v, acc, 0, 0, 0);
#pragma unroll
        for (int r = 0; r < 4; ++r) {
          int row = m0 + q * 4 + r, col = nt * 16 + c;
          hA[row][64 + col] = f2b(acc[r] + biasE[1][col]);
        }
      }
    }
    __syncthreads();
    // S3: msg MLP layer1 (K=128) -> silu -> ef1
    {
      short8 a0 = *(const short8*)&hA[m0 + c][q * 8];
      short8 a1 = *(const short8*)&hA[m0 + c][32 + q * 8];
      short8 a2 = *(const short8*)&hA[m0 + c][64 + q * 8];
      short8 a3 = *(const short8*)&hA[m0 + c][96 + q * 8];
#pragma unroll
      for (int nt = 0; nt < 4; ++nt) {
        const u16* wp = &wM1[(nt * 16 + c) * 136];
        f32x4 acc = __builtin_amdgcn_mfma_f32_16x16x32_bf16(a0, *(const short8*)(wp + q * 8), z, 0, 0, 0);
        acc = __builtin_amdgcn_mfma_f32_16x16x32_bf16(a1, *(const short8*)(wp + 32 + q * 8), acc, 0, 0, 0);
        acc = __builtin_amdgcn_mfma_f32_16x16x32_bf16(a2, *(const short8*)(wp + 64 + q * 8), acc, 0, 0, 0);
        acc = __builtin_amdgcn_mfma_f32_16x16x32_bf16(a3, *(const short8*)(wp + 96 + q * 8), acc, 0, 0, 0);
#pragma unroll
        for (int r = 0; r < 4; ++r) {
          int row = m0 + q * 4 + r, col = nt * 16 + c;
          ef1[row][col] = f2b(silu_f(acc[r] + biasE[2][col]));
        }
      }
    }
    __syncthreads();
    // S4: msg MLP layer2 (K=64) -> atomic scatter
    {
      short8 a0 = *(const short8*)&ef1[m0 + c][q * 8];
      short8 a1 = *(const short8*)&ef1[m0 + c][32 + q * 8];
      int rtg[4];
#pragma unroll
      for (int r = 0; r < 4; ++r) rtg[r] = tgt_s[m0 + q * 4 + r];
#pragma unroll
      for (int nt = 0; nt < 4; ++nt) {
        short8 b0 = *(const short8*)&wM2[(nt * 16 + c) * 72 + q * 8];
        short8 b1v = *(const short8*)&wM2[(nt * 16 + c) * 72 + 32 + q * 8];
        f32x4 acc = __builtin_amdgcn_mfma_f32_16x16x32_bf16(a0, b0, z, 0, 0, 0);
        acc = __builtin_amdgcn_mfma_f32_16x16x32_bf16(a1, b1v, acc, 0, 0, 0);
#pragma unroll
        for (int r = 0; r < 4; ++r) {
          int tg = rtg[r];
          if (tg >= 0 && tg < G) {
            int col = nt * 16 + c;
            unsafeAtomicAdd(sums + (long)tg * 64 + col, acc[r] + biasE[3][col]);
          }
        }
      }
    }
  }
}

// ---------------------------------------------------------------------------
// Kernel 4: scatter-mean + update MLP (f32) -> f32 out [G,64]
// ---------------------------------------------------------------------------
__global__ __launch_bounds__(256) void upd_mlp(
    const float* __restrict__ sums, const float* __restrict__ counts,
    const float* __restrict__ fw, float* __restrict__ out, int nrows)
{
  __shared__ float xs[64][68];
  __shared__ float w1s[64][68];
  __shared__ float w2s[64][68];
  __shared__ float b1s[64];
  __shared__ float b2s[64];
  const int t = threadIdx.x;
  const long rbase = (long)blockIdx.x * 64;
  for (int i = t; i < 4096; i += 256) {
    int k = i >> 6, cc = i & 63;
    w1s[k][cc] = fw[FW_UW1 + i];
    w2s[k][cc] = fw[FW_UW2 + i];
  }
  if (t < 64) { b1s[t] = fw[FW_UB1 + t]; b2s[t] = fw[FW_UB2 + t]; }
  {
    int row = t >> 2, ch = t & 3;
    long rg = rbase + row;
    if (rg < nrows) {
      float inv = 1.0f / fmaxf(counts[rg], 1.0f);
      const float* p = sums + rg * 64 + ch * 16;
#pragma unroll
      for (int m = 0; m < 16; ++m) xs[row][ch * 16 + m] = p[m] * inv;
    } else {
#pragma unroll
      for (int m = 0; m < 16; ++m) xs[row][ch * 16 + m] = 0.f;
    }
  }
  __syncthreads();
  const int r0 = (t >> 4) * 4, c0 = (t & 15) * 4;
  float acc[4][4];
#pragma unroll
  for (int i = 0; i < 4; ++i)
#pragma unroll
    for (int j = 0; j < 4; ++j) acc[i][j] = b1s[c0 + j];
  for (int k = 0; k < 64; ++k) {
    float w0 = w1s[k][c0], w1v = w1s[k][c0 + 1], w2v = w1s[k][c0 + 2], w3v = w1s[k][c0 + 3];
#pragma unroll
    for (int i = 0; i < 4; ++i) {
      float a = xs[r0 + i][k];
      acc[i][0] = fmaf(a, w0, acc[i][0]);
      acc[i][1] = fmaf(a, w1v, acc[i][1]);
      acc[i][2] = fmaf(a, w2v, acc[i][2]);
      acc[i][3] = fmaf(a, w3v, acc[i][3]);
    }
  }
  __syncthreads();
#pragma unroll
  for (int i = 0; i < 4; ++i)
#pragma unroll
    for (int j = 0; j < 4; ++j) xs[r0 + i][c0 + j] = silu_f(acc[i][j]);
  __syncthreads();
  float acc2[4][4];
#pragma unroll
  for (int i = 0; i < 4; ++i)
#pragma unroll
    for (int j = 0; j < 4; ++j) acc2[i][j] = b2s[c0 + j];
  for (int k = 0; k < 64; ++k) {
    float w0 = w2s[k][c0], w1v = w2s[k][c0 + 1], w2v = w2s[k][c0 + 2], w3v = w2s[k][c0 + 3];
#pragma unroll
    for (int i = 0; i < 4; ++i) {
      float a = xs[r0 + i][k];
      acc2[i][0] = fmaf(a, w0, acc2[i][0]);
      acc2[i][1] = fmaf(a, w1v, acc2[i][1]);
      acc2[i][2] = fmaf(a, w2v, acc2[i][2]);
      acc2[i][3] = fmaf(a, w3v, acc2[i][3]);
    }
  }
#pragma unroll
  for (int i = 0; i < 4; ++i) {
    long rg = rbase + r0 + i;
    if (rg < nrows) {
#pragma unroll
      for (int j = 0; j < 4; ++j) out[rg * 64 + c0 + j] = acc2[i][j];
    }
  }
}

// ---------------------------------------------------------------------------
extern "C" void kernel_launch(void* const* d_in, const int* in_sizes, int n_in,
                              void* d_out, int out_size, void* d_ws, size_t ws_size,
                              hipStream_t stream) {
  const int N = in_sizes[1] / 3;
  const int G = in_sizes[2] / 3;
  const long E = (long)in_sizes[4] / 2;

  char* ws = (char*)d_ws;
  int* flags = (int*)ws;                                    // 32 ints, pad 256B
  float* sums = (float*)(ws + 256);
  float* counts = (float*)(ws + 256 + (size_t)G * 256);
  const size_t off_h = 256 + (size_t)G * 256 + (size_t)G * 4;
  u16* h_node = (u16*)(ws + off_h);
  const size_t off_img = off_h + (size_t)N * 128;
  u16* img = (u16*)(ws + off_img);
  const size_t off_fw = off_img + (size_t)IMG_TOTAL * 2;
  float* fw = (float*)(ws + off_fw);

  // zero flags + sums + counts
  hipMemsetAsync(ws, 0, off_h, stream);

  Ptrs a;
  const int map[20] = {0,1,2,3, 5,6,7,8, 9,10,11,12, 13,14,15,16, 17,18,19,20};
  for (int i = 0; i < 20; ++i) { a.p[i] = d_in[map[i]]; a.n[i] = in_sizes[map[i]]; }

  detect_k<<<20, 256, 0, stream>>>(a, flags);
  prep_k<<<(IMG_TOTAL + FW_TOTAL + 255) / 256, 256, 0, stream>>>(a, flags, img, fw);
  node_mlp<<<(N + 63) / 64, 256, 0, stream>>>(d_in[0], flags, fw, h_node, N);
  edge_kernel<<<(int)((E + ETILES * 64 - 1) / (ETILES * 64)), 256, 0, stream>>>(
      d_in[1], d_in[2], d_in[3], (const int*)d_in[4], h_node, img, fw, flags,
      sums, counts, E, G);
  upd_mlp<<<(G + 63) / 64, 256, 0, stream>>>(sums, counts, fw, (float*)d_out, G);
}